// Round 15
// baseline (630.353 us; speedup 1.0000x reference)
//
#include <hip/hip_runtime.h>
#include <hip/hip_fp16.h>
#include <math.h>

#define FEATURES 2048
#define MROWS 4000
#define NPAD 4096
#define BROWS 8192

typedef unsigned short u16;
typedef unsigned int u32;

typedef __attribute__((ext_vector_type(8))) _Float16 f16x8;   // fp16 frag (gemm2)
typedef __attribute__((ext_vector_type(8))) short s16x8;      // bf16 frag (gemm1)
typedef __attribute__((ext_vector_type(4))) float f32x4;

__device__ __forceinline__ u16 f2h(float f) {
  union { _Float16 h; u16 u; } cv;
  cv.h = (_Float16)f;  // v_cvt_f16_f32, RNE
  return cv.u;
}
__device__ __forceinline__ u16 f2bf(float f) {
  u32 u = __float_as_uint(f);
  u32 r = (u + 0x7FFFu + ((u >> 16) & 1u)) >> 16;  // RNE to bf16
  return (u16)r;
}
__device__ __forceinline__ float bf2f(u16 h) {
  return __uint_as_float(((u32)h) << 16);
}

// async global->LDS, 16B per lane; LDS dest must be wave-uniform (+lane*16)
#define GLD16(g, l)                                                            \
  __builtin_amdgcn_global_load_lds(                                            \
      (const __attribute__((address_space(1))) u32*)(g),                       \
      (__attribute__((address_space(3))) u32*)(l), 16, 0, 0)

// LEDGER:
//  r11: XCD-span block swizzle REGRESSED (FETCH 200->660 MB). Don't re-add.
//  r13: 32x32x16 MFMA REGRESSED (+2.5e7 bank conflicts). Keep 16x16x32.
//  r6/r7: raw-barrier + counted vmcnt REGRESSED (compiler goes conservative).
//  r14 WIN: STAGE between ds_reads and MFMA: gemm1 390->362 (MfmaUtil 52%).
//  r15: same reorder on gemm2 + pointer strength-reduction on gemm1 staging.

// ---------------------------------------------------------------------------
// fp32 rows -> bf16 hi + bf16 lo (unscaled) + row L2 norm (fp32 exact).
// Rows >= nrows: zeros, norm=1.
__global__ __launch_bounds__(256) void conv_split_bf16_kernel(
    const float* __restrict__ src, u16* __restrict__ hi, u16* __restrict__ lo,
    float* __restrict__ norms, int nrows) {
  __shared__ float red[4];
  const int row = blockIdx.x;
  const int tid = threadIdx.x;
  ushort4* hp = (ushort4*)(hi + (size_t)row * FEATURES);
  ushort4* lp = (ushort4*)(lo + (size_t)row * FEATURES);
  float ss = 0.f;
  if (row < nrows) {
    const float4* sp = (const float4*)(src + (size_t)row * FEATURES);
#pragma unroll
    for (int p = 0; p < 2; ++p) {
      const int idx = tid + p * 256;  // 512 float4 per row
      float4 f = sp[idx];
      ushort4 h, l;
      h.x = f2bf(f.x); l.x = f2bf(f.x - bf2f(h.x)); ss += f.x * f.x;
      h.y = f2bf(f.y); l.y = f2bf(f.y - bf2f(h.y)); ss += f.y * f.y;
      h.z = f2bf(f.z); l.z = f2bf(f.z - bf2f(h.z)); ss += f.z * f.z;
      h.w = f2bf(f.w); l.w = f2bf(f.w - bf2f(h.w)); ss += f.w * f.w;
      hp[idx] = h;
      lp[idx] = l;
    }
  } else {
    const ushort4 zz = {0, 0, 0, 0};
#pragma unroll
    for (int p = 0; p < 2; ++p) {
      hp[tid + p * 256] = zz;
      lp[tid + p * 256] = zz;
    }
  }
#pragma unroll
  for (int o = 32; o; o >>= 1) ss += __shfl_xor(ss, o);
  if ((tid & 63) == 0) red[tid >> 6] = ss;
  __syncthreads();
  if (tid == 0) {
    float tot = red[0] + red[1] + red[2] + red[3];
    norms[row] = (row < nrows) ? sqrtf(tot) : 1.0f;
  }
}

// ---------------------------------------------------------------------------
// memT[j][k] = mem[k][j] as fp16, [FEATURES][NPAD], k>=MROWS zero-padded.
__global__ __launch_bounds__(256) void transpose_f16_kernel(
    const float* __restrict__ mem, u16* __restrict__ mt) {
  __shared__ float tile[64][65];
  const int tid = threadIdx.x;
  const int ti = blockIdx.x;
  const int tj = blockIdx.y;
  const int c = tid & 63;
  const int r0 = tid >> 6;
#pragma unroll
  for (int i = 0; i < 16; ++i) {
    const int r = i * 4 + r0;
    const int gr = ti * 64 + r;
    float v = 0.f;
    if (gr < MROWS) v = mem[(size_t)gr * FEATURES + tj * 64 + c];
    tile[r][c] = v;
  }
  __syncthreads();
#pragma unroll
  for (int i = 0; i < 16; ++i) {
    const int r = i * 4 + r0;
    mt[(size_t)(tj * 64 + r) * NPAD + ti * 64 + c] = f2h(tile[c][r]);
  }
}

// ---------------------------------------------------------------------------
// GEMM1 bf16 3-pass split, single fp32 accumulator. 256x256 block, BK=32,
// 8 waves, wave tile 128x64, 16x16x32 MFMA. r14 schedule (ds_reads ->
// STAGE(next) -> MFMA -> barrier). r15: staging addresses strength-reduced
// to 8 persistent pointers advanced +=32/step (cuts per-step addr VALU).
__global__ __launch_bounds__(512, 2) void gemm1_kernel(
    const u16* __restrict__ Ah, const u16* __restrict__ Al,
    const u16* __restrict__ Bh, const u16* __restrict__ Bl,
    const float* __restrict__ zn, const float* __restrict__ mn,
    float* __restrict__ C) {
  __shared__ __align__(16) u16 sAh[2 * 8192];
  __shared__ __align__(16) u16 sAl[2 * 8192];
  __shared__ __align__(16) u16 sBh[2 * 8192];
  __shared__ __align__(16) u16 sBl[2 * 8192];
  const int tid = threadIdx.x;
  const int wid = tid >> 6;   // 0..7
  const int lane = tid & 63;
  const int brow = blockIdx.x * 256;
  const int bcol = blockIdx.y * 256;
  const int wr = wid >> 2;    // 0..1  (M half: 128 rows)
  const int wc = wid & 3;     // 0..3  (N quarter: 64 cols)
  const int fr = lane & 15, fq = lane >> 4;
  const int fqa = (fq ^ ((fr >> 1) & 3)) * 8;  // swizzled LDS read chunk

  f32x4 acc[8][4];
#pragma unroll
  for (int m = 0; m < 8; ++m)
#pragma unroll
    for (int n = 0; n < 4; ++n) acc[m][n] = (f32x4){0.f, 0.f, 0.f, 0.f};

  const int r_st = tid >> 2;                               // 0..127
  const int c_sw = (((tid & 3) ^ ((tid >> 3) & 3)) << 3);  // swizzled src col

  // Persistent staging pointers (advanced +=32 per staged K-step).
  const u16* pA0 = Ah + (size_t)(brow + r_st) * FEATURES + c_sw;
  const u16* pA1 = pA0 + 128 * FEATURES;
  const u16* pL0 = Al + (size_t)(brow + r_st) * FEATURES + c_sw;
  const u16* pL1 = pL0 + 128 * FEATURES;
  const u16* pB0 = Bh + (size_t)(bcol + r_st) * FEATURES + c_sw;
  const u16* pB1 = pB0 + 128 * FEATURES;
  const u16* pM0 = Bl + (size_t)(bcol + r_st) * FEATURES + c_sw;
  const u16* pM1 = pM0 + 128 * FEATURES;

#define STAGE1(cur)                                                            \
  {                                                                            \
    const int l0 = (cur) * 8192 + wid * 512;                                   \
    GLD16(pA0, sAh + l0);                                                      \
    GLD16(pL0, sAl + l0);                                                      \
    GLD16(pB0, sBh + l0);                                                      \
    GLD16(pM0, sBl + l0);                                                      \
    GLD16(pA1, sAh + l0 + 4096);                                               \
    GLD16(pL1, sAl + l0 + 4096);                                               \
    GLD16(pB1, sBh + l0 + 4096);                                               \
    GLD16(pM1, sBl + l0 + 4096);                                               \
    pA0 += 32; pA1 += 32; pL0 += 32; pL1 += 32;                                \
    pB0 += 32; pB1 += 32; pM0 += 32; pM1 += 32;                                \
  }

  STAGE1(0);
  __syncthreads();
  for (int kt = 0; kt < 64; ++kt) {
    const int cur = kt & 1;
    const int bo = cur * 8192;
    // 1) fragment ds_reads (lgkm queue fills)
    s16x8 bh[4], bl[4];
#pragma unroll
    for (int n = 0; n < 4; ++n) {
      const int ro = bo + (wc * 64 + n * 16 + fr) * 32 + fqa;
      bh[n] = *(const s16x8*)(sBh + ro);
      bl[n] = *(const s16x8*)(sBl + ro);
    }
    s16x8 ah[8], al[8];
#pragma unroll
    for (int m = 0; m < 8; ++m) {
      const int ro = bo + (wr * 128 + m * 16 + fr) * 32 + fqa;
      ah[m] = *(const s16x8*)(sAh + ro);
      al[m] = *(const s16x8*)(sAl + ro);
    }
    // 2) issue next-tile staging (lands during the MFMA block)
    if (kt < 63) STAGE1(cur ^ 1);
    // 3) MFMA block
#pragma unroll
    for (int m = 0; m < 8; ++m)
#pragma unroll
      for (int n = 0; n < 4; ++n) {
        acc[m][n] = __builtin_amdgcn_mfma_f32_16x16x32_bf16(
            ah[m], bh[n], acc[m][n], 0, 0, 0);
        acc[m][n] = __builtin_amdgcn_mfma_f32_16x16x32_bf16(
            al[m], bh[n], acc[m][n], 0, 0, 0);
        acc[m][n] = __builtin_amdgcn_mfma_f32_16x16x32_bf16(
            ah[m], bl[n], acc[m][n], 0, 0, 0);
      }
    __syncthreads();
  }
#undef STAGE1

#pragma unroll
  for (int m = 0; m < 8; ++m) {
#pragma unroll
    for (int r = 0; r < 4; ++r) {
      const int row = brow + wr * 128 + m * 16 + fq * 4 + r;
      const float z = zn[row];
#pragma unroll
      for (int n = 0; n < 4; ++n) {
        const int col = bcol + wc * 64 + n * 16 + fr;
        const float denom = fmaxf(z * mn[col], 1e-8f);
        C[(size_t)row * NPAD + col] = acc[m][n][r] / denom;
      }
    }
  }
}

// ---------------------------------------------------------------------------
// Softmax + threshold-shrink + L1 normalize; one block per row.
// Writes fp16 w IN PLACE over the logits row (row stride stays 16 KB).
__global__ __launch_bounds__(256) void softmax_kernel(float* __restrict__ logits) {
  __shared__ float red[4];
  const int row = blockIdx.x;
  const int tid = threadIdx.x;
  const float* lp = logits + (size_t)row * NPAD;
  u16* W = (u16*)logits + (size_t)row * (2 * NPAD);  // overlay, fp16
  float v[16];
  float lmax = -3.4e38f;
#pragma unroll
  for (int i = 0; i < 16; ++i) {
    const int c = tid + i * 256;
    v[i] = (c < MROWS) ? lp[c] : -3.4e38f;
    lmax = fmaxf(lmax, v[i]);
  }
#pragma unroll
  for (int o = 32; o; o >>= 1) lmax = fmaxf(lmax, __shfl_xor(lmax, o));
  if ((tid & 63) == 0) red[tid >> 6] = lmax;
  __syncthreads();
  lmax = fmaxf(fmaxf(red[0], red[1]), fmaxf(red[2], red[3]));

  float s = 0.f;
#pragma unroll
  for (int i = 0; i < 16; ++i) {
    const int c = tid + i * 256;
    if (c < MROWS) {
      v[i] = expf(v[i] - lmax);
      s += v[i];
    } else {
      v[i] = 0.f;
    }
  }
#pragma unroll
  for (int o = 32; o; o >>= 1) s += __shfl_xor(s, o);
  __syncthreads();
  if ((tid & 63) == 0) red[tid >> 6] = s;
  __syncthreads();
  const float Z = red[0] + red[1] + red[2] + red[3];

  const float THR = (float)(1.0 / 4000.0);
  float s2 = 0.f;
#pragma unroll
  for (int i = 0; i < 16; ++i) {
    float w = v[i] / Z;
    const float d = w - THR;
    w = fmaxf(d, 0.f) * w / (fabsf(d) + 1e-12f);
    v[i] = w;
    s2 += w;
  }
#pragma unroll
  for (int o = 32; o; o >>= 1) s2 += __shfl_xor(s2, o);
  __syncthreads();
  if ((tid & 63) == 0) red[tid >> 6] = s2;
  __syncthreads();
  const float S = fmaxf(red[0] + red[1] + red[2] + red[3], 1e-12f);

#pragma unroll
  for (int i = 0; i < 16; ++i) {
    const int c = tid + i * 256;
    W[c] = f2h(v[i] / S);
  }
}

// ---------------------------------------------------------------------------
// GEMM2 (128x128 / 4-wave), r15: r14-style schedule — ds_reads -> STAGE ->
// MFMA -> barrier. A = w overlay on logits buffer (row stride 2*NPAD u16).
__global__ __launch_bounds__(256) void gemm2_kernel(
    const u16* __restrict__ A, const u16* __restrict__ B,
    float* __restrict__ C) {
  __shared__ __align__(16) u16 sA[2 * 4096];
  __shared__ __align__(16) u16 sB[2 * 4096];
  const int tid = threadIdx.x;
  const int wid = tid >> 6;
  const int lane = tid & 63;
  const int brow = blockIdx.x * 128;
  const int bcol = blockIdx.y * 128;
  const int wr = wid >> 1, wc = wid & 1;
  const int fr = lane & 15, fq = lane >> 4;
  const int fqa = (fq ^ ((fr >> 1) & 3)) * 8;

  f32x4 acc[4][4];
#pragma unroll
  for (int m = 0; m < 4; ++m)
#pragma unroll
    for (int n = 0; n < 4; ++n) acc[m][n] = (f32x4){0.f, 0.f, 0.f, 0.f};

  const int r_st = tid >> 2;
  const int c_sw = (((tid & 3) ^ ((tid >> 3) & 3)) << 3);

  // Persistent staging pointers.
  const u16* pA0 = A + (size_t)(brow + r_st) * (2 * NPAD) + c_sw;
  const u16* pA1 = pA0 + 64 * (2 * NPAD);
  const u16* pB0 = B + (size_t)(bcol + r_st) * NPAD + c_sw;
  const u16* pB1 = pB0 + 64 * NPAD;

#define STAGE2(cur)                                                            \
  {                                                                            \
    const int l0 = (cur) * 4096 + wid * 512;                                   \
    GLD16(pA0, sA + l0);                                                       \
    GLD16(pB0, sB + l0);                                                       \
    GLD16(pA1, sA + l0 + 2048);                                                \
    GLD16(pB1, sB + l0 + 2048);                                                \
    pA0 += 32; pA1 += 32; pB0 += 32; pB1 += 32;                                \
  }

  STAGE2(0);
  __syncthreads();
  for (int kt = 0; kt < 128; ++kt) {
    const int cur = kt & 1;
    const int bo = cur * 4096;
    f16x8 af[4], bf[4];
#pragma unroll
    for (int m = 0; m < 4; ++m)
      af[m] = *(const f16x8*)(sA + bo + (wr * 64 + m * 16 + fr) * 32 + fqa);
#pragma unroll
    for (int n = 0; n < 4; ++n)
      bf[n] = *(const f16x8*)(sB + bo + (wc * 64 + n * 16 + fr) * 32 + fqa);
    if (kt < 127) STAGE2(cur ^ 1);
#pragma unroll
    for (int m = 0; m < 4; ++m)
#pragma unroll
      for (int n = 0; n < 4; ++n)
        acc[m][n] = __builtin_amdgcn_mfma_f32_16x16x32_f16(
            af[m], bf[n], acc[m][n], 0, 0, 0);
    __syncthreads();
  }
#undef STAGE2

#pragma unroll
  for (int m = 0; m < 4; ++m) {
#pragma unroll
    for (int r = 0; r < 4; ++r) {
      const int row = brow + wr * 64 + m * 16 + fq * 4 + r;
#pragma unroll
      for (int n = 0; n < 4; ++n) {
        const int col = bcol + wc * 64 + n * 16 + fr;
        C[(size_t)row * FEATURES + col] = acc[m][n][r];
      }
    }
  }
}

// ---------------------------------------------------------------------------
extern "C" void kernel_launch(void* const* d_in, const int* in_sizes, int n_in,
                              void* d_out, int out_size, void* d_ws, size_t ws_size,
                              hipStream_t stream) {
  const float* x = (const float*)d_in[0];
  const float* mem = (const float*)d_in[1];
  float* out = (float*)d_out;
  char* ws = (char*)d_ws;

  size_t o = 0;
  u16* mh = (u16*)(ws + o); o += (size_t)NPAD * FEATURES * 2;   // 16.8 MB
  u16* ml = (u16*)(ws + o); o += (size_t)NPAD * FEATURES * 2;   // 16.8 MB
  u16* mt = (u16*)(ws + o); o += (size_t)FEATURES * NPAD * 2;   // 16.8 MB
  float* zn = (float*)(ws + o); o += (size_t)BROWS * 4;
  float* mn = (float*)(ws + o); o += (size_t)NPAD * 4;
  const size_t base = o;

  // Largest row-chunk whose x hi/lo + fp32-logits fit the remaining workspace.
  // CH multiple of 256 (gemm1 block-M).
  int CH = BROWS;
  size_t need = 0;
  for (;; CH >>= 1) {
    need = base + (size_t)CH * FEATURES * 2 * 2 + (size_t)CH * NPAD * 4;
    if (need <= ws_size || CH == 256) break;
  }
  if (need > ws_size) return;  // cannot run
  u16* xh = (u16*)(ws + base);
  u16* xl = (u16*)(ws + base + (size_t)CH * FEATURES * 2);
  float* lg = (float*)(ws + base + (size_t)CH * FEATURES * 4);

  conv_split_bf16_kernel<<<NPAD, 256, 0, stream>>>(mem, mh, ml, mn, MROWS);
  transpose_f16_kernel<<<dim3(NPAD / 64, FEATURES / 64), 256, 0, stream>>>(mem, mt);

  for (int r0 = 0; r0 < BROWS; r0 += CH) {
    conv_split_bf16_kernel<<<CH, 256, 0, stream>>>(x + (size_t)r0 * FEATURES, xh, xl, zn, CH);
    gemm1_kernel<<<dim3(CH / 256, NPAD / 256), 512, 0, stream>>>(xh, xl, mh, ml, zn, mn, lg);
    softmax_kernel<<<CH, 256, 0, stream>>>(lg);
    gemm2_kernel<<<dim3(CH / 128, FEATURES / 128), 256, 0, stream>>>(
        (const u16*)lg, mt, out + (size_t)r0 * FEATURES);
  }
}

// Round 16
// 557.973 us; speedup vs baseline: 1.1297x; 1.1297x over previous
//
#include <hip/hip_runtime.h>
#include <hip/hip_fp16.h>
#include <math.h>

#define FEATURES 2048
#define MROWS 4000
#define NPAD 4096
#define BROWS 8192

typedef unsigned short u16;
typedef unsigned int u32;

typedef __attribute__((ext_vector_type(8))) _Float16 f16x8;   // fp16 frag (gemm2)
typedef __attribute__((ext_vector_type(8))) short s16x8;      // bf16 frag (gemm1)
typedef __attribute__((ext_vector_type(4))) float f32x4;

__device__ __forceinline__ u16 f2h(float f) {
  union { _Float16 h; u16 u; } cv;
  cv.h = (_Float16)f;  // v_cvt_f16_f32, RNE
  return cv.u;
}
__device__ __forceinline__ u16 f2bf(float f) {
  u32 u = __float_as_uint(f);
  u32 r = (u + 0x7FFFu + ((u >> 16) & 1u)) >> 16;  // RNE to bf16
  return (u16)r;
}
__device__ __forceinline__ float bf2f(u16 h) {
  return __uint_as_float(((u32)h) << 16);
}

// async global->LDS, 16B per lane; LDS dest must be wave-uniform (+lane*16)
#define GLD16(g, l)                                                            \
  __builtin_amdgcn_global_load_lds(                                            \
      (const __attribute__((address_space(1))) u32*)(g),                       \
      (__attribute__((address_space(3))) u32*)(l), 16, 0, 0)

// LEDGER:
//  r11: XCD-span block swizzle REGRESSED (FETCH 200->660 MB). Don't re-add.
//  r13: 32x32x16 MFMA REGRESSED (+2.5e7 bank conflicts). Keep 16x16x32.
//  r6/r7: raw-barrier + counted vmcnt REGRESSED (compiler goes conservative).
//  r14 WIN: STAGE between ds_reads and MFMA on gemm1 (long MFMA window):
//           390->362. r15: SAME reorder on gemm2 (short window) REGRESSED
//           +60 us — only apply when MFMA block is long enough to cover
//           load latency. Pointer strength-reduction: null.
//  Best pieces: gemm1 r15-form (362); gemm2 256sq/8-wave STAGE-top (r10,
//           rest-of-pipeline 201).

// ---------------------------------------------------------------------------
// fp32 rows -> bf16 hi + bf16 lo (unscaled) + row L2 norm (fp32 exact).
// Rows >= nrows: zeros, norm=1.
__global__ __launch_bounds__(256) void conv_split_bf16_kernel(
    const float* __restrict__ src, u16* __restrict__ hi, u16* __restrict__ lo,
    float* __restrict__ norms, int nrows) {
  __shared__ float red[4];
  const int row = blockIdx.x;
  const int tid = threadIdx.x;
  ushort4* hp = (ushort4*)(hi + (size_t)row * FEATURES);
  ushort4* lp = (ushort4*)(lo + (size_t)row * FEATURES);
  float ss = 0.f;
  if (row < nrows) {
    const float4* sp = (const float4*)(src + (size_t)row * FEATURES);
#pragma unroll
    for (int p = 0; p < 2; ++p) {
      const int idx = tid + p * 256;  // 512 float4 per row
      float4 f = sp[idx];
      ushort4 h, l;
      h.x = f2bf(f.x); l.x = f2bf(f.x - bf2f(h.x)); ss += f.x * f.x;
      h.y = f2bf(f.y); l.y = f2bf(f.y - bf2f(h.y)); ss += f.y * f.y;
      h.z = f2bf(f.z); l.z = f2bf(f.z - bf2f(h.z)); ss += f.z * f.z;
      h.w = f2bf(f.w); l.w = f2bf(f.w - bf2f(h.w)); ss += f.w * f.w;
      hp[idx] = h;
      lp[idx] = l;
    }
  } else {
    const ushort4 zz = {0, 0, 0, 0};
#pragma unroll
    for (int p = 0; p < 2; ++p) {
      hp[tid + p * 256] = zz;
      lp[tid + p * 256] = zz;
    }
  }
#pragma unroll
  for (int o = 32; o; o >>= 1) ss += __shfl_xor(ss, o);
  if ((tid & 63) == 0) red[tid >> 6] = ss;
  __syncthreads();
  if (tid == 0) {
    float tot = red[0] + red[1] + red[2] + red[3];
    norms[row] = (row < nrows) ? sqrtf(tot) : 1.0f;
  }
}

// ---------------------------------------------------------------------------
// memT[j][k] = mem[k][j] as fp16, [FEATURES][NPAD], k>=MROWS zero-padded.
__global__ __launch_bounds__(256) void transpose_f16_kernel(
    const float* __restrict__ mem, u16* __restrict__ mt) {
  __shared__ float tile[64][65];
  const int tid = threadIdx.x;
  const int ti = blockIdx.x;
  const int tj = blockIdx.y;
  const int c = tid & 63;
  const int r0 = tid >> 6;
#pragma unroll
  for (int i = 0; i < 16; ++i) {
    const int r = i * 4 + r0;
    const int gr = ti * 64 + r;
    float v = 0.f;
    if (gr < MROWS) v = mem[(size_t)gr * FEATURES + tj * 64 + c];
    tile[r][c] = v;
  }
  __syncthreads();
#pragma unroll
  for (int i = 0; i < 16; ++i) {
    const int r = i * 4 + r0;
    mt[(size_t)(tj * 64 + r) * NPAD + ti * 64 + c] = f2h(tile[c][r]);
  }
}

// ---------------------------------------------------------------------------
// GEMM1 bf16 3-pass split, single fp32 accumulator. 256x256 block, BK=32,
// 8 waves, wave tile 128x64, 16x16x32 MFMA. r14 schedule (ds_reads ->
// STAGE(next) -> MFMA -> barrier) + persistent staging pointers. 362 us.
__global__ __launch_bounds__(512, 2) void gemm1_kernel(
    const u16* __restrict__ Ah, const u16* __restrict__ Al,
    const u16* __restrict__ Bh, const u16* __restrict__ Bl,
    const float* __restrict__ zn, const float* __restrict__ mn,
    float* __restrict__ C) {
  __shared__ __align__(16) u16 sAh[2 * 8192];
  __shared__ __align__(16) u16 sAl[2 * 8192];
  __shared__ __align__(16) u16 sBh[2 * 8192];
  __shared__ __align__(16) u16 sBl[2 * 8192];
  const int tid = threadIdx.x;
  const int wid = tid >> 6;   // 0..7
  const int lane = tid & 63;
  const int brow = blockIdx.x * 256;
  const int bcol = blockIdx.y * 256;
  const int wr = wid >> 2;    // 0..1  (M half: 128 rows)
  const int wc = wid & 3;     // 0..3  (N quarter: 64 cols)
  const int fr = lane & 15, fq = lane >> 4;
  const int fqa = (fq ^ ((fr >> 1) & 3)) * 8;  // swizzled LDS read chunk

  f32x4 acc[8][4];
#pragma unroll
  for (int m = 0; m < 8; ++m)
#pragma unroll
    for (int n = 0; n < 4; ++n) acc[m][n] = (f32x4){0.f, 0.f, 0.f, 0.f};

  const int r_st = tid >> 2;                               // 0..127
  const int c_sw = (((tid & 3) ^ ((tid >> 3) & 3)) << 3);  // swizzled src col

  // Persistent staging pointers (advanced +=32 per staged K-step).
  const u16* pA0 = Ah + (size_t)(brow + r_st) * FEATURES + c_sw;
  const u16* pA1 = pA0 + 128 * FEATURES;
  const u16* pL0 = Al + (size_t)(brow + r_st) * FEATURES + c_sw;
  const u16* pL1 = pL0 + 128 * FEATURES;
  const u16* pB0 = Bh + (size_t)(bcol + r_st) * FEATURES + c_sw;
  const u16* pB1 = pB0 + 128 * FEATURES;
  const u16* pM0 = Bl + (size_t)(bcol + r_st) * FEATURES + c_sw;
  const u16* pM1 = pM0 + 128 * FEATURES;

#define STAGE1(cur)                                                            \
  {                                                                            \
    const int l0 = (cur) * 8192 + wid * 512;                                   \
    GLD16(pA0, sAh + l0);                                                      \
    GLD16(pL0, sAl + l0);                                                      \
    GLD16(pB0, sBh + l0);                                                      \
    GLD16(pM0, sBl + l0);                                                      \
    GLD16(pA1, sAh + l0 + 4096);                                               \
    GLD16(pL1, sAl + l0 + 4096);                                               \
    GLD16(pB1, sBh + l0 + 4096);                                               \
    GLD16(pM1, sBl + l0 + 4096);                                               \
    pA0 += 32; pA1 += 32; pL0 += 32; pL1 += 32;                                \
    pB0 += 32; pB1 += 32; pM0 += 32; pM1 += 32;                                \
  }

  STAGE1(0);
  __syncthreads();
  for (int kt = 0; kt < 64; ++kt) {
    const int cur = kt & 1;
    const int bo = cur * 8192;
    // 1) fragment ds_reads (lgkm queue fills)
    s16x8 bh[4], bl[4];
#pragma unroll
    for (int n = 0; n < 4; ++n) {
      const int ro = bo + (wc * 64 + n * 16 + fr) * 32 + fqa;
      bh[n] = *(const s16x8*)(sBh + ro);
      bl[n] = *(const s16x8*)(sBl + ro);
    }
    s16x8 ah[8], al[8];
#pragma unroll
    for (int m = 0; m < 8; ++m) {
      const int ro = bo + (wr * 128 + m * 16 + fr) * 32 + fqa;
      ah[m] = *(const s16x8*)(sAh + ro);
      al[m] = *(const s16x8*)(sAl + ro);
    }
    // 2) issue next-tile staging (lands during the MFMA block)
    if (kt < 63) STAGE1(cur ^ 1);
    // 3) MFMA block (96 MFMA/wave — long window covers staging latency)
#pragma unroll
    for (int m = 0; m < 8; ++m)
#pragma unroll
      for (int n = 0; n < 4; ++n) {
        acc[m][n] = __builtin_amdgcn_mfma_f32_16x16x32_bf16(
            ah[m], bh[n], acc[m][n], 0, 0, 0);
        acc[m][n] = __builtin_amdgcn_mfma_f32_16x16x32_bf16(
            al[m], bh[n], acc[m][n], 0, 0, 0);
        acc[m][n] = __builtin_amdgcn_mfma_f32_16x16x32_bf16(
            ah[m], bl[n], acc[m][n], 0, 0, 0);
      }
    __syncthreads();
  }
#undef STAGE1

#pragma unroll
  for (int m = 0; m < 8; ++m) {
#pragma unroll
    for (int r = 0; r < 4; ++r) {
      const int row = brow + wr * 128 + m * 16 + fq * 4 + r;
      const float z = zn[row];
#pragma unroll
      for (int n = 0; n < 4; ++n) {
        const int col = bcol + wc * 64 + n * 16 + fr;
        const float denom = fmaxf(z * mn[col], 1e-8f);
        C[(size_t)row * NPAD + col] = acc[m][n][r] / denom;
      }
    }
  }
}

// ---------------------------------------------------------------------------
// Softmax + threshold-shrink + L1 normalize; one block per row.
// Writes fp16 w IN PLACE over the logits row (row stride stays 16 KB).
__global__ __launch_bounds__(256) void softmax_kernel(float* __restrict__ logits) {
  __shared__ float red[4];
  const int row = blockIdx.x;
  const int tid = threadIdx.x;
  const float* lp = logits + (size_t)row * NPAD;
  u16* W = (u16*)logits + (size_t)row * (2 * NPAD);  // overlay, fp16
  float v[16];
  float lmax = -3.4e38f;
#pragma unroll
  for (int i = 0; i < 16; ++i) {
    const int c = tid + i * 256;
    v[i] = (c < MROWS) ? lp[c] : -3.4e38f;
    lmax = fmaxf(lmax, v[i]);
  }
#pragma unroll
  for (int o = 32; o; o >>= 1) lmax = fmaxf(lmax, __shfl_xor(lmax, o));
  if ((tid & 63) == 0) red[tid >> 6] = lmax;
  __syncthreads();
  lmax = fmaxf(fmaxf(red[0], red[1]), fmaxf(red[2], red[3]));

  float s = 0.f;
#pragma unroll
  for (int i = 0; i < 16; ++i) {
    const int c = tid + i * 256;
    if (c < MROWS) {
      v[i] = expf(v[i] - lmax);
      s += v[i];
    } else {
      v[i] = 0.f;
    }
  }
#pragma unroll
  for (int o = 32; o; o >>= 1) s += __shfl_xor(s, o);
  __syncthreads();
  if ((tid & 63) == 0) red[tid >> 6] = s;
  __syncthreads();
  const float Z = red[0] + red[1] + red[2] + red[3];

  const float THR = (float)(1.0 / 4000.0);
  float s2 = 0.f;
#pragma unroll
  for (int i = 0; i < 16; ++i) {
    float w = v[i] / Z;
    const float d = w - THR;
    w = fmaxf(d, 0.f) * w / (fabsf(d) + 1e-12f);
    v[i] = w;
    s2 += w;
  }
#pragma unroll
  for (int o = 32; o; o >>= 1) s2 += __shfl_xor(s2, o);
  __syncthreads();
  if ((tid & 63) == 0) red[tid >> 6] = s2;
  __syncthreads();
  const float S = fmaxf(red[0] + red[1] + red[2] + red[3], 1e-12f);

#pragma unroll
  for (int i = 0; i < 16; ++i) {
    const int c = tid + i * 256;
    W[c] = f2h(v[i] / S);
  }
}

// ---------------------------------------------------------------------------
// GEMM2 (r10-proven 256x256 / 8-wave / STAGE-at-top): out = w @ mt^T.
// A = w overlay on logits buffer (row stride 2*NPAD u16). 64 KB LDS.
__global__ __launch_bounds__(512, 2) void gemm2_kernel(
    const u16* __restrict__ A, const u16* __restrict__ B,
    float* __restrict__ C) {
  __shared__ __align__(16) u16 sA[2 * 8192];
  __shared__ __align__(16) u16 sB[2 * 8192];
  const int tid = threadIdx.x;
  const int wid = tid >> 6;
  const int lane = tid & 63;
  const int brow = blockIdx.x * 256;
  const int bcol = blockIdx.y * 256;
  const int wr = wid >> 2, wc = wid & 3;
  const int fr = lane & 15, fq = lane >> 4;
  const int fqa = (fq ^ ((fr >> 1) & 3)) * 8;

  f32x4 acc[8][4];
#pragma unroll
  for (int m = 0; m < 8; ++m)
#pragma unroll
    for (int n = 0; n < 4; ++n) acc[m][n] = (f32x4){0.f, 0.f, 0.f, 0.f};

  const int r_st = tid >> 2;
  const int c_sw = (((tid & 3) ^ ((tid >> 3) & 3)) << 3);

#define STAGE2(cur, k0)                                                        \
  {                                                                            \
    _Pragma("unroll") for (int p = 0; p < 2; ++p) {                            \
      const int r = r_st + p * 128;                                            \
      const size_t offA = (size_t)(brow + r) * (2 * NPAD) + ((k0) + c_sw);     \
      const size_t offB = (size_t)(bcol + r) * NPAD + ((k0) + c_sw);           \
      const int ldso = (cur) * 8192 + p * 4096 + wid * 512;                    \
      GLD16(A + offA, sA + ldso);                                              \
      GLD16(B + offB, sB + ldso);                                              \
    }                                                                          \
  }

#define G2_COMPUTE(cur)                                                        \
  {                                                                            \
    const int bo = (cur) * 8192;                                               \
    f16x8 bf[4];                                                               \
    _Pragma("unroll") for (int n = 0; n < 4; ++n)                              \
      bf[n] = *(const f16x8*)(sB + bo + (wc * 64 + n * 16 + fr) * 32 + fqa);   \
    _Pragma("unroll") for (int m = 0; m < 8; ++m) {                            \
      const f16x8 af =                                                         \
          *(const f16x8*)(sA + bo + (wr * 128 + m * 16 + fr) * 32 + fqa);      \
      _Pragma("unroll") for (int n = 0; n < 4; ++n)                            \
        acc[m][n] = __builtin_amdgcn_mfma_f32_16x16x32_f16(                    \
            af, bf[n], acc[m][n], 0, 0, 0);                                    \
    }                                                                          \
  }

  STAGE2(0, 0);
  __syncthreads();
  for (int kt = 0; kt < 128; ++kt) {
    const int cur = kt & 1;
    if (kt < 127) STAGE2(cur ^ 1, (kt + 1) * 32);
    G2_COMPUTE(cur);
    __syncthreads();
  }
#undef STAGE2
#undef G2_COMPUTE

#pragma unroll
  for (int m = 0; m < 8; ++m) {
#pragma unroll
    for (int r = 0; r < 4; ++r) {
      const int row = brow + wr * 128 + m * 16 + fq * 4 + r;
#pragma unroll
      for (int n = 0; n < 4; ++n) {
        const int col = bcol + wc * 64 + n * 16 + fr;
        C[(size_t)row * FEATURES + col] = acc[m][n][r];
      }
    }
  }
}

// ---------------------------------------------------------------------------
extern "C" void kernel_launch(void* const* d_in, const int* in_sizes, int n_in,
                              void* d_out, int out_size, void* d_ws, size_t ws_size,
                              hipStream_t stream) {
  const float* x = (const float*)d_in[0];
  const float* mem = (const float*)d_in[1];
  float* out = (float*)d_out;
  char* ws = (char*)d_ws;

  size_t o = 0;
  u16* mh = (u16*)(ws + o); o += (size_t)NPAD * FEATURES * 2;   // 16.8 MB
  u16* ml = (u16*)(ws + o); o += (size_t)NPAD * FEATURES * 2;   // 16.8 MB
  u16* mt = (u16*)(ws + o); o += (size_t)FEATURES * NPAD * 2;   // 16.8 MB
  float* zn = (float*)(ws + o); o += (size_t)BROWS * 4;
  float* mn = (float*)(ws + o); o += (size_t)NPAD * 4;
  const size_t base = o;

  // Largest row-chunk whose x hi/lo + fp32-logits fit the remaining workspace.
  // CH multiple of 256 (gemm block-M).
  int CH = BROWS;
  size_t need = 0;
  for (;; CH >>= 1) {
    need = base + (size_t)CH * FEATURES * 2 * 2 + (size_t)CH * NPAD * 4;
    if (need <= ws_size || CH == 256) break;
  }
  if (need > ws_size) return;  // cannot run
  u16* xh = (u16*)(ws + base);
  u16* xl = (u16*)(ws + base + (size_t)CH * FEATURES * 2);
  float* lg = (float*)(ws + base + (size_t)CH * FEATURES * 4);

  conv_split_bf16_kernel<<<NPAD, 256, 0, stream>>>(mem, mh, ml, mn, MROWS);
  transpose_f16_kernel<<<dim3(NPAD / 64, FEATURES / 64), 256, 0, stream>>>(mem, mt);

  for (int r0 = 0; r0 < BROWS; r0 += CH) {
    conv_split_bf16_kernel<<<CH, 256, 0, stream>>>(x + (size_t)r0 * FEATURES, xh, xl, zn, CH);
    gemm1_kernel<<<dim3(CH / 256, NPAD / 256), 512, 0, stream>>>(xh, xl, mh, ml, zn, mn, lg);
    softmax_kernel<<<CH, 256, 0, stream>>>(lg);
    gemm2_kernel<<<dim3(CH / 256, FEATURES / 256), 512, 0, stream>>>(
        (const u16*)lg, mt, out + (size_t)r0 * FEATURES);
  }
}